// Round 12
// baseline (1537.218 us; speedup 1.0000x reference)
//
#include <hip/hip_runtime.h>
#include <stdint.h>

// MoE: E=8 routed (top-2) + 2 shared experts, H=2048, I=5120, T=2048 tokens.
// Sparse expert compute in bf16 MFMA (16x16x32), fp32 router.
// R12: R9 grid + schedule (best known: 1035us) MINUS the A-operand LDS
//      round-trip: A fragments are loaded DIRECTLY from global (xb / h are
//      bf16, L1/L2-hot, 16B/lane contiguous) -> LDS traffic per K-step drops
//      88KB -> 40KB/block (the measured ~1030cy step == LDS BW floor).
//      B (fp32 weights) keeps the cvt_pk -> padded-LDS dbuf path.

#define E_ 8
#define H_ 2048
#define I_ 5120
#define T_ 2048
#define NSLOT 10           // 8 routed + 2 shared
#define LDA 36             // 32 cols + 4 pad (ushort); 72B rows

typedef __attribute__((ext_vector_type(4))) float f32x4;
typedef __attribute__((ext_vector_type(8))) __bf16 bf16x8;
typedef __attribute__((ext_vector_type(4))) unsigned int u32x4;
typedef __attribute__((ext_vector_type(2))) unsigned int u32x2;

__device__ __forceinline__ unsigned short f2bf(float f) {
  unsigned u = __builtin_bit_cast(unsigned, f);
  u += 0x7FFFu + ((u >> 16) & 1u);   // round-to-nearest-even
  return (unsigned short)(u >> 16);
}

__device__ __forceinline__ bf16x8 ldfrag(const unsigned short* p) {
  // 8 bf16 = 16B at 8B alignment (72B row stride): two b64 reads
  u32x2 lo = *(const u32x2*)p;
  u32x2 hi = *(const u32x2*)(p + 4);
  u32x4 v; v[0] = lo[0]; v[1] = lo[1]; v[2] = hi[0]; v[3] = hi[1];
  return __builtin_bit_cast(bf16x8, v);
}

// 4 fp32 -> 4 bf16 via 2x v_cvt_pk_bf16_f32 (RNE), one b64 LDS write
__device__ __forceinline__ void st_bf4(unsigned short* p, f32x4 v) {
  unsigned r0, r1;
  asm("v_cvt_pk_bf16_f32 %0, %1, %2" : "=v"(r0) : "v"(v[0]), "v"(v[1]));
  asm("v_cvt_pk_bf16_f32 %0, %1, %2" : "=v"(r1) : "v"(v[2]), "v"(v[3]));
  u32x2 w; w[0] = r0; w[1] = r1;
  *(u32x2*)p = w;
}

// ---------------- x fp32 -> bf16 pre-cast (RNE, same as staging did) --------
__global__ __launch_bounds__(256) void k_castx(const float* __restrict__ x,
                                               unsigned short* __restrict__ xb) {
  const int i = (blockIdx.x * 256 + threadIdx.x) * 8;
  f32x4 a = *(const f32x4*)(x + i);
  f32x4 b = *(const f32x4*)(x + i + 4);
  unsigned r0, r1, r2, r3;
  asm("v_cvt_pk_bf16_f32 %0, %1, %2" : "=v"(r0) : "v"(a[0]), "v"(a[1]));
  asm("v_cvt_pk_bf16_f32 %0, %1, %2" : "=v"(r1) : "v"(a[2]), "v"(a[3]));
  asm("v_cvt_pk_bf16_f32 %0, %1, %2" : "=v"(r2) : "v"(b[0]), "v"(b[1]));
  asm("v_cvt_pk_bf16_f32 %0, %1, %2" : "=v"(r3) : "v"(b[2]), "v"(b[3]));
  u32x4 o; o[0] = r0; o[1] = r1; o[2] = r2; o[3] = r3;
  *(u32x4*)(xb + i) = o;
}

// ---------------- router: fp32 logits, sigmoid, top-2, renormalize ----------
__global__ __launch_bounds__(64) void k_router(const float* __restrict__ x,
                                               const float* __restrict__ wr,
                                               int* __restrict__ tki,
                                               float* __restrict__ tkw) {
  const int t = blockIdx.x, lane = threadIdx.x;
  const float* xr = x + (size_t)t * H_;
  float lg[E_];
#pragma unroll
  for (int e = 0; e < E_; ++e) {
    const float* w = wr + (size_t)e * H_;
    float acc = 0.f;
    for (int k = lane; k < H_; k += 64) acc += xr[k] * w[k];
#pragma unroll
    for (int off = 32; off > 0; off >>= 1) acc += __shfl_down(acc, off);
    lg[e] = acc;  // valid on lane 0
  }
  if (lane == 0) {
    float sc[E_];
#pragma unroll
    for (int e = 0; e < E_; ++e) sc[e] = 1.f / (1.f + expf(-lg[e]));
    int b0 = 0;
#pragma unroll
    for (int e = 1; e < E_; ++e) if (sc[e] > sc[b0]) b0 = e;
    int b1 = -1;
#pragma unroll
    for (int e = 0; e < E_; ++e) {
      if (e == b0) continue;
      if (b1 < 0 || sc[e] > sc[b1]) b1 = e;
    }
    float s0 = sc[b0], s1 = sc[b1], inv = 1.f / (s0 + s1);
    tki[2 * t] = b0; tki[2 * t + 1] = b1;
    tkw[2 * t] = s0 * inv; tkw[2 * t + 1] = s1 * inv;
  }
}

// ------------- per-slot token lists (compaction), shared = identity ---------
__global__ __launch_bounds__(64) void k_lists(const int* __restrict__ tki,
                                              const float* __restrict__ tkw,
                                              int* __restrict__ elist,
                                              float* __restrict__ ew,
                                              int* __restrict__ ecnt) {
  const int s = blockIdx.x, lane = threadIdx.x;
  if (s < E_) {
    int base = 0;
    for (int c = 0; c < T_ / 64; ++c) {
      int t = c * 64 + lane;
      int i0 = tki[2 * t], i1 = tki[2 * t + 1];
      int flag = (i0 == s) ? 1 : ((i1 == s) ? 2 : 0);
      unsigned long long m = __ballot(flag != 0);
      int pre = __popcll(m & ((1ull << lane) - 1ull));
      if (flag) {
        elist[s * T_ + base + pre] = t;
        ew[s * T_ + base + pre] = tkw[2 * t + flag - 1];
      }
      base += __popcll(m);
    }
    int padded = (base + 127) & ~127;
    for (int p = base + lane; p < padded; p += 64) { elist[s * T_ + p] = 0; ew[s * T_ + p] = 0.f; }
    if (lane == 0) ecnt[s] = base;
  } else {
    for (int i = lane; i < T_; i += 64) { elist[s * T_ + i] = i; ew[s * T_ + i] = 1.f; }
    if (lane == 0) ecnt[s] = T_;
  }
}

__global__ void k_bases(const int* __restrict__ ecnt, int* __restrict__ sbase) {
  if (threadIdx.x == 0 && blockIdx.x == 0) {
    int b = 0;
    for (int s = 0; s < NSLOT; ++s) { sbase[s] = b; b += (ecnt[s] + 127) & ~127; }
  }
}

// -------- gate/up GEMM: h = ew * silu(x.wg^T) * (x.wu^T), bf16 out ----------
// tile 256(tok) x 64(I) x BK=32 over K=H; 8 waves (4r x 2c); dual accums.
// A fragments read DIRECTLY from global xb (no LDS); B via cvt_pk + LDS dbuf.
__global__ __launch_bounds__(512, 4) void k_gateup(
    const unsigned short* __restrict__ xb,
    const float* __restrict__ wg_all, const float* __restrict__ wu_all,
    const float* __restrict__ sg_all, const float* __restrict__ su_all,
    const int* __restrict__ elist, const float* __restrict__ ew,
    const int* __restrict__ ecnt,
    const int* __restrict__ sbase, unsigned short* __restrict__ h) {
  const int s = blockIdx.z;
  const int cnt = ecnt[s];
  const int r0 = blockIdx.y * 256;
  if (r0 >= cnt) return;
  const int n0 = blockIdx.x * 64;
  const float* gw; const float* uw;
  if (s < E_) { gw = wg_all + (size_t)s * I_ * H_; uw = wu_all + (size_t)s * I_ * H_; }
  else        { gw = sg_all + (size_t)(s - E_) * I_ * H_; uw = su_all + (size_t)(s - E_) * I_ * H_; }
  const int* lst = elist + s * T_;
  const int hrow0 = sbase[s] + r0;

  __shared__ unsigned short sG[2][64 * LDA];
  __shared__ unsigned short sU[2][64 * LDA];

  const int tid = threadIdx.x;
  const int w = tid >> 6, lane = tid & 63;
  const int wr = w >> 1, wc = w & 1;
  const int fr = lane & 15, k8 = lane >> 4;

  // A fragment pointers: lane (fr,k8) of frag m reads 16B of token row
  // (wr*64 + m*16 + fr) at column kt*32 + k8*8. Proven ldfrag mapping,
  // source moved from LDS to global xb.
  const unsigned short* a0p; const unsigned short* a1p;
  const unsigned short* a2p; const unsigned short* a3p;
  {
    int rr = wr * 64 + fr;
    int l0 = r0 + rr;      if (l0 >= cnt) l0 = r0;
    int l1 = r0 + rr + 16; if (l1 >= cnt) l1 = r0;
    int l2 = r0 + rr + 32; if (l2 >= cnt) l2 = r0;
    int l3 = r0 + rr + 48; if (l3 >= cnt) l3 = r0;
    a0p = xb + (size_t)lst[l0] * H_ + k8 * 8;
    a1p = xb + (size_t)lst[l1] * H_ + k8 * 8;
    a2p = xb + (size_t)lst[l2] * H_ + k8 * 8;
    a3p = xb + (size_t)lst[l3] * H_ + k8 * 8;
  }

  // B staging: 64x32 fp32 each, 4 floats/thread each
  const int br = tid >> 3, bc0 = (tid & 7) * 4;
  const float* gp = gw + (size_t)(n0 + br) * H_ + bc0;
  const float* up = uw + (size_t)(n0 + br) * H_ + bc0;
  f32x4 rg, ru;

  f32x4 accg[4][2], accu[4][2];
#pragma unroll
  for (int m = 0; m < 4; ++m)
#pragma unroll
    for (int n = 0; n < 2; ++n) {
      accg[m][n] = (f32x4){0.f, 0.f, 0.f, 0.f};
      accu[m][n] = (f32x4){0.f, 0.f, 0.f, 0.f};
    }

  auto loadNext = [&]() {
    rg = *(const f32x4*)gp; ru = *(const f32x4*)up;
    gp += 32; up += 32;
  };
  auto stage = [&](int b) {
    st_bf4(sG[b] + br * LDA + bc0, rg);
    st_bf4(sU[b] + br * LDA + bc0, ru);
  };
  auto compute = [&](int b) {
    u32x4 a0 = *(const u32x4*)a0p; a0p += 32;
    u32x4 a1 = *(const u32x4*)a1p; a1p += 32;
    u32x4 a2 = *(const u32x4*)a2p; a2p += 32;
    u32x4 a3 = *(const u32x4*)a3p; a3p += 32;
    bf16x8 af[4];
    af[0] = __builtin_bit_cast(bf16x8, a0);
    af[1] = __builtin_bit_cast(bf16x8, a1);
    af[2] = __builtin_bit_cast(bf16x8, a2);
    af[3] = __builtin_bit_cast(bf16x8, a3);
    bf16x8 gf[2], uf[2];
#pragma unroll
    for (int n = 0; n < 2; ++n) {
      gf[n] = ldfrag(sG[b] + (wc * 32 + n * 16 + fr) * LDA + k8 * 8);
      uf[n] = ldfrag(sU[b] + (wc * 32 + n * 16 + fr) * LDA + k8 * 8);
    }
#pragma unroll
    for (int m = 0; m < 4; ++m)
#pragma unroll
      for (int n = 0; n < 2; ++n) {
        accg[m][n] = __builtin_amdgcn_mfma_f32_16x16x32_bf16(af[m], gf[n], accg[m][n], 0, 0, 0);
        accu[m][n] = __builtin_amdgcn_mfma_f32_16x16x32_bf16(af[m], uf[n], accu[m][n], 0, 0, 0);
      }
  };

  const int KT = H_ / 32;  // 64
  loadNext();              // kt=0
  stage(0);
  loadNext();              // kt=1 in flight
  __syncthreads();
  int cur = 0;
  for (int kt = 0; kt < KT; ++kt) {
    compute(cur);
    if (kt + 1 < KT) {
      stage(cur ^ 1);
      if (kt + 2 < KT) loadNext();  // issue BEFORE barrier (R9 schedule)
      __syncthreads();
      cur ^= 1;
    }
  }

  // epilogue: h = ew * silu(g)*u, bf16, masked to valid rows
#pragma unroll
  for (int m = 0; m < 4; ++m)
#pragma unroll
    for (int r = 0; r < 4; ++r) {
      int rit = wr * 64 + m * 16 + k8 * 4 + r;
      if (r0 + rit < cnt) {
        float wgt = ew[s * T_ + r0 + rit];
        unsigned short* hrow = h + (size_t)(hrow0 + rit) * I_ + n0 + wc * 32;
#pragma unroll
        for (int n = 0; n < 2; ++n) {
          float g = accg[m][n][r], uv = accu[m][n][r];
          float hv = g / (1.f + expf(-g)) * uv * wgt;
          hrow[n * 16 + fr] = f2bf(hv);
        }
      }
    }
}

// -------- down GEMM: out[tok] += h . wd^T (atomicAdd over slots) ------------
// tile 256(tok) x 128(H) x BK=32 over K=I; 8 waves (4r x 2c).
// A (pre-weighted h, bf16) fragments direct from global; B via LDS dbuf.
__global__ __launch_bounds__(512, 4) void k_down(
    const unsigned short* __restrict__ h,
    const float* __restrict__ wd_all, const float* __restrict__ sd_all,
    const int* __restrict__ elist,
    const int* __restrict__ ecnt, const int* __restrict__ sbase,
    float* __restrict__ out) {
  const int s = blockIdx.z;
  const int cnt = ecnt[s];
  const int r0 = blockIdx.y * 256;
  if (r0 >= cnt) return;
  const int n0 = blockIdx.x * 128;
  const float* bw = (s < E_) ? wd_all + (size_t)s * H_ * I_
                             : sd_all + (size_t)(s - E_) * H_ * I_;
  const int hrow0 = sbase[s] + r0;

  __shared__ unsigned short sB[2][128 * LDA];

  const int tid = threadIdx.x;
  const int w = tid >> 6, lane = tid & 63;
  const int wr = w >> 1, wc = w & 1;
  const int fr = lane & 15, k8 = lane >> 4;

  // A fragment pointers into h (rows >= cnt read in-bounds garbage, masked)
  const unsigned short* a0p = h + (size_t)(hrow0 + wr * 64 + fr) * I_ + k8 * 8;
  const unsigned short* a1p = a0p + (size_t)16 * I_;
  const unsigned short* a2p = a0p + (size_t)32 * I_;
  const unsigned short* a3p = a0p + (size_t)48 * I_;

  // B staging: 128x32 fp32, 8 floats/thread
  const int brr = tid >> 2, bc0 = (tid & 3) * 8;
  const float* bp = bw + (size_t)(n0 + brr) * I_ + bc0;
  f32x4 rb0, rb1;

  f32x4 acc[4][4];
#pragma unroll
  for (int m = 0; m < 4; ++m)
#pragma unroll
    for (int n = 0; n < 4; ++n) acc[m][n] = (f32x4){0.f, 0.f, 0.f, 0.f};

  auto loadNext = [&]() {
    rb0 = *(const f32x4*)(bp); rb1 = *(const f32x4*)(bp + 4); bp += 32;
  };
  auto stage = [&](int b) {
    st_bf4(sB[b] + brr * LDA + bc0, rb0);
    st_bf4(sB[b] + brr * LDA + bc0 + 4, rb1);
  };
  auto compute = [&](int b) {
    u32x4 a0 = *(const u32x4*)a0p; a0p += 32;
    u32x4 a1 = *(const u32x4*)a1p; a1p += 32;
    u32x4 a2 = *(const u32x4*)a2p; a2p += 32;
    u32x4 a3 = *(const u32x4*)a3p; a3p += 32;
    bf16x8 af[4];
    af[0] = __builtin_bit_cast(bf16x8, a0);
    af[1] = __builtin_bit_cast(bf16x8, a1);
    af[2] = __builtin_bit_cast(bf16x8, a2);
    af[3] = __builtin_bit_cast(bf16x8, a3);
    bf16x8 bf[4];
#pragma unroll
    for (int n = 0; n < 4; ++n) bf[n] = ldfrag(sB[b] + (wc * 64 + n * 16 + fr) * LDA + k8 * 8);
#pragma unroll
    for (int m = 0; m < 4; ++m)
#pragma unroll
      for (int n = 0; n < 4; ++n)
        acc[m][n] = __builtin_amdgcn_mfma_f32_16x16x32_bf16(af[m], bf[n], acc[m][n], 0, 0, 0);
  };

  const int KT = I_ / 32;  // 160
  loadNext();              // kt=0
  stage(0);
  loadNext();              // kt=1 in flight
  __syncthreads();
  int cur = 0;
  for (int kt = 0; kt < KT; ++kt) {
    compute(cur);
    if (kt + 1 < KT) {
      stage(cur ^ 1);
      if (kt + 2 < KT) loadNext();  // issue BEFORE barrier
      __syncthreads();
      cur ^= 1;
    }
  }

  const int* lst = elist + s * T_;
#pragma unroll
  for (int m = 0; m < 4; ++m)
#pragma unroll
    for (int r = 0; r < 4; ++r) {
      int rit = wr * 64 + m * 16 + k8 * 4 + r;
      if (r0 + rit < cnt) {
        int t = lst[r0 + rit];
        float* orow = out + (size_t)t * H_ + n0 + wc * 64 + fr;
#pragma unroll
        for (int n = 0; n < 4; ++n) atomicAdd(orow + n * 16, acc[m][n][r]);
      }
    }
}

extern "C" void kernel_launch(void* const* d_in, const int* in_sizes, int n_in,
                              void* d_out, int out_size, void* d_ws, size_t ws_size,
                              hipStream_t stream) {
  const float* x  = (const float*)d_in[0];
  const float* wr = (const float*)d_in[1];
  const float* wg = (const float*)d_in[2];
  const float* wu = (const float*)d_in[3];
  const float* wd = (const float*)d_in[4];
  const float* sg = (const float*)d_in[5];
  const float* su = (const float*)d_in[6];
  const float* sd = (const float*)d_in[7];
  float* out = (float*)d_out;
  char* ws = (char*)d_ws;

  // workspace layout (needs ~103.1 MB)
  int*   tki   = (int*)(ws);                 // T*2 ints
  float* tkw   = (float*)(ws + 16384);       // T*2 floats
  int*   elist = (int*)(ws + 32768);         // NSLOT*T ints
  float* ew    = (float*)(ws + 114688);      // NSLOT*T floats
  int*   ecnt  = (int*)(ws + 196608);        // NSLOT ints
  int*   sbase = (int*)(ws + 196864);        // NSLOT ints
  unsigned short* xb = (unsigned short*)(ws + 262144);            // T*H bf16 (8.4 MB)
  unsigned short* h  = (unsigned short*)(ws + 262144 + 8388608);  // <=9216 rows x I bf16

  k_castx<<<T_ * H_ / (256 * 8), 256, 0, stream>>>(x, xb);
  k_router<<<T_, 64, 0, stream>>>(x, wr, tki, tkw);
  k_lists<<<NSLOT, 64, 0, stream>>>(tki, tkw, elist, ew, ecnt);
  k_bases<<<1, 1, 0, stream>>>(ecnt, sbase);
  k_gateup<<<dim3(I_ / 64, T_ / 256, NSLOT), 512, 0, stream>>>(
      xb, wg, wu, sg, su, elist, ew, ecnt, sbase, h);
  hipMemsetAsync(out, 0, (size_t)T_ * H_ * sizeof(float), stream);
  k_down<<<dim3(H_ / 128, T_ / 256, NSLOT), 512, 0, stream>>>(
      h, wd, sd, elist, ecnt, sbase, out);
}

// Round 13
// 978.925 us; speedup vs baseline: 1.5703x; 1.5703x over previous
//
#include <hip/hip_runtime.h>
#include <stdint.h>

// MoE: E=8 routed (top-2) + 2 shared experts, H=2048, I=5120, T=2048 tokens.
// Sparse expert compute in bf16 MFMA (16x16x32), fp32 router.
// R13: R9 structure/schedule, but 1024-thread blocks (16 waves, 4r x 4c) to
//      double BN at constant acc regs: gateup BN=128 (A L2 traffic halved),
//      down BN=256 (same). LDS un-padded (LDA=32, exactly 64KB) with 16B
//      chunk XOR swizzle (chunk ^= (row ^ row>>2) & 3) -> max 2-way bank
//      aliasing (free) and single ds_read_b128 per fragment.

#define E_ 8
#define H_ 2048
#define I_ 5120
#define T_ 2048
#define NSLOT 10           // 8 routed + 2 shared

typedef __attribute__((ext_vector_type(4))) float f32x4;
typedef __attribute__((ext_vector_type(8))) __bf16 bf16x8;
typedef __attribute__((ext_vector_type(4))) unsigned int u32x4;
typedef __attribute__((ext_vector_type(2))) unsigned int u32x2;

__device__ __forceinline__ int sw(int r) { return (r ^ (r >> 2)) & 3; }

__device__ __forceinline__ unsigned short f2bf(float f) {
  unsigned u = __builtin_bit_cast(unsigned, f);
  u += 0x7FFFu + ((u >> 16) & 1u);   // round-to-nearest-even
  return (unsigned short)(u >> 16);
}

// 4 fp32 -> 4 bf16 (RNE) packed in u32x2 via v_cvt_pk_bf16_f32
__device__ __forceinline__ u32x2 cvt4(f32x4 v) {
  unsigned r0, r1;
  asm("v_cvt_pk_bf16_f32 %0, %1, %2" : "=v"(r0) : "v"(v[0]), "v"(v[1]));
  asm("v_cvt_pk_bf16_f32 %0, %1, %2" : "=v"(r1) : "v"(v[2]), "v"(v[3]));
  u32x2 w; w[0] = r0; w[1] = r1;
  return w;
}

// ---------------- x fp32 -> bf16 pre-cast (RNE, same as staging did) --------
__global__ __launch_bounds__(256) void k_castx(const float* __restrict__ x,
                                               unsigned short* __restrict__ xb) {
  const int i = (blockIdx.x * 256 + threadIdx.x) * 8;
  f32x4 a = *(const f32x4*)(x + i);
  f32x4 b = *(const f32x4*)(x + i + 4);
  u32x2 lo = cvt4(a), hi = cvt4(b);
  u32x4 o; o[0] = lo[0]; o[1] = lo[1]; o[2] = hi[0]; o[3] = hi[1];
  *(u32x4*)(xb + i) = o;
}

// ---------------- router: fp32 logits, sigmoid, top-2, renormalize ----------
__global__ __launch_bounds__(64) void k_router(const float* __restrict__ x,
                                               const float* __restrict__ wr,
                                               int* __restrict__ tki,
                                               float* __restrict__ tkw) {
  const int t = blockIdx.x, lane = threadIdx.x;
  const float* xr = x + (size_t)t * H_;
  float lg[E_];
#pragma unroll
  for (int e = 0; e < E_; ++e) {
    const float* w = wr + (size_t)e * H_;
    float acc = 0.f;
    for (int k = lane; k < H_; k += 64) acc += xr[k] * w[k];
#pragma unroll
    for (int off = 32; off > 0; off >>= 1) acc += __shfl_down(acc, off);
    lg[e] = acc;  // valid on lane 0
  }
  if (lane == 0) {
    float sc[E_];
#pragma unroll
    for (int e = 0; e < E_; ++e) sc[e] = 1.f / (1.f + expf(-lg[e]));
    int b0 = 0;
#pragma unroll
    for (int e = 1; e < E_; ++e) if (sc[e] > sc[b0]) b0 = e;
    int b1 = -1;
#pragma unroll
    for (int e = 0; e < E_; ++e) {
      if (e == b0) continue;
      if (b1 < 0 || sc[e] > sc[b1]) b1 = e;
    }
    float s0 = sc[b0], s1 = sc[b1], inv = 1.f / (s0 + s1);
    tki[2 * t] = b0; tki[2 * t + 1] = b1;
    tkw[2 * t] = s0 * inv; tkw[2 * t + 1] = s1 * inv;
  }
}

// ------------- per-slot token lists (compaction), shared = identity ---------
__global__ __launch_bounds__(64) void k_lists(const int* __restrict__ tki,
                                              const float* __restrict__ tkw,
                                              int* __restrict__ elist,
                                              float* __restrict__ ew,
                                              int* __restrict__ ecnt) {
  const int s = blockIdx.x, lane = threadIdx.x;
  if (s < E_) {
    int base = 0;
    for (int c = 0; c < T_ / 64; ++c) {
      int t = c * 64 + lane;
      int i0 = tki[2 * t], i1 = tki[2 * t + 1];
      int flag = (i0 == s) ? 1 : ((i1 == s) ? 2 : 0);
      unsigned long long m = __ballot(flag != 0);
      int pre = __popcll(m & ((1ull << lane) - 1ull));
      if (flag) {
        elist[s * T_ + base + pre] = t;
        ew[s * T_ + base + pre] = tkw[2 * t + flag - 1];
      }
      base += __popcll(m);
    }
    int padded = (base + 255) & ~255;
    for (int p = base + lane; p < padded; p += 64) { elist[s * T_ + p] = 0; ew[s * T_ + p] = 0.f; }
    if (lane == 0) ecnt[s] = base;
  } else {
    for (int i = lane; i < T_; i += 64) { elist[s * T_ + i] = i; ew[s * T_ + i] = 1.f; }
    if (lane == 0) ecnt[s] = T_;
  }
}

__global__ void k_bases(const int* __restrict__ ecnt, int* __restrict__ sbase) {
  if (threadIdx.x == 0 && blockIdx.x == 0) {
    int b = 0;
    for (int s = 0; s < NSLOT; ++s) { sbase[s] = b; b += (ecnt[s] + 255) & ~255; }
  }
}

// -------- gate/up GEMM: h = ew * silu(x.wg^T) * (x.wu^T), bf16 out ----------
// tile 256(tok) x 128(I) x BK=32 over K=H; 16 waves (4r x 4c); dual accums.
// Dbuf LDS (swizzled, 64KB), 1 barrier/K-step, loads before barrier.
__global__ __launch_bounds__(1024, 4) void k_gateup(
    const unsigned short* __restrict__ xb,
    const float* __restrict__ wg_all, const float* __restrict__ wu_all,
    const float* __restrict__ sg_all, const float* __restrict__ su_all,
    const int* __restrict__ elist, const float* __restrict__ ew,
    const int* __restrict__ ecnt,
    const int* __restrict__ sbase, unsigned short* __restrict__ h) {
  const int s = blockIdx.z;
  const int cnt = ecnt[s];
  const int r0 = blockIdx.y * 256;
  if (r0 >= cnt) return;
  const int n0 = blockIdx.x * 128;
  const float* gw; const float* uw;
  if (s < E_) { gw = wg_all + (size_t)s * I_ * H_; uw = wu_all + (size_t)s * I_ * H_; }
  else        { gw = sg_all + (size_t)(s - E_) * I_ * H_; uw = su_all + (size_t)(s - E_) * I_ * H_; }
  const int* lst = elist + s * T_;
  const int hrow0 = sbase[s] + r0;

  // LDS as 16B chunks: A 256 rows x 4 chunks, G/U 128 x 4. Total 64KB.
  __shared__ u32x4 sA[2][256 * 4];
  __shared__ u32x4 sG[2][128 * 4];
  __shared__ u32x4 sU[2][128 * 4];

  const int tid = threadIdx.x;
  const int w = tid >> 6, lane = tid & 63;
  const int wr = w >> 2, wc = w & 3;
  const int fr = lane & 15, k8 = lane >> 4;

  // A staging: row ar, chunk ca (8 bf16 = 16B per thread)
  const int ar = tid >> 2, ca = tid & 3;
  int li = r0 + ar; if (li >= cnt) li = r0;   // clamp: rows >= cnt masked later
  const unsigned short* xp = xb + (size_t)lst[li] * H_ + ca * 8;
  // G/U staging: row br, 4 fp32 per thread (half chunk)
  const int br = tid >> 3, cb = (tid & 7) >> 1, bh = tid & 1;
  const float* gp = gw + (size_t)(n0 + br) * H_ + (tid & 7) * 4;
  const float* up = uw + (size_t)(n0 + br) * H_ + (tid & 7) * 4;

  u32x4 ra; f32x4 rg, ru;

  f32x4 accg[4][2], accu[4][2];
#pragma unroll
  for (int m = 0; m < 4; ++m)
#pragma unroll
    for (int n = 0; n < 2; ++n) {
      accg[m][n] = (f32x4){0.f, 0.f, 0.f, 0.f};
      accu[m][n] = (f32x4){0.f, 0.f, 0.f, 0.f};
    }

  auto loadNext = [&]() {
    ra = *(const u32x4*)xp; rg = *(const f32x4*)gp; ru = *(const f32x4*)up;
    xp += 32; gp += 32; up += 32;
  };
  auto stage = [&](int b) {
    sA[b][ar * 4 + (ca ^ sw(ar))] = ra;
    ((u32x2*)&sG[b][br * 4 + (cb ^ sw(br))])[bh] = cvt4(rg);
    ((u32x2*)&sU[b][br * 4 + (cb ^ sw(br))])[bh] = cvt4(ru);
  };
  auto compute = [&](int b) {
    bf16x8 af[4], gf[2], uf[2];
#pragma unroll
    for (int m = 0; m < 4; ++m) {
      int r = wr * 64 + m * 16 + fr;
      af[m] = __builtin_bit_cast(bf16x8, sA[b][r * 4 + (k8 ^ sw(r))]);
    }
#pragma unroll
    for (int n = 0; n < 2; ++n) {
      int r = wc * 32 + n * 16 + fr;
      gf[n] = __builtin_bit_cast(bf16x8, sG[b][r * 4 + (k8 ^ sw(r))]);
      uf[n] = __builtin_bit_cast(bf16x8, sU[b][r * 4 + (k8 ^ sw(r))]);
    }
#pragma unroll
    for (int m = 0; m < 4; ++m)
#pragma unroll
      for (int n = 0; n < 2; ++n) {
        accg[m][n] = __builtin_amdgcn_mfma_f32_16x16x32_bf16(af[m], gf[n], accg[m][n], 0, 0, 0);
        accu[m][n] = __builtin_amdgcn_mfma_f32_16x16x32_bf16(af[m], uf[n], accu[m][n], 0, 0, 0);
      }
  };

  const int KT = H_ / 32;  // 64
  loadNext();              // kt=0
  stage(0);
  loadNext();              // kt=1 in flight
  __syncthreads();
  int cur = 0;
  for (int kt = 0; kt < KT; ++kt) {
    compute(cur);
    if (kt + 1 < KT) {
      stage(cur ^ 1);
      if (kt + 2 < KT) loadNext();  // issue BEFORE barrier (R9 schedule)
      __syncthreads();
      cur ^= 1;
    }
  }

  // epilogue: h = ew * silu(g)*u, bf16, masked to valid rows
#pragma unroll
  for (int m = 0; m < 4; ++m)
#pragma unroll
    for (int r = 0; r < 4; ++r) {
      int rit = wr * 64 + m * 16 + k8 * 4 + r;
      if (r0 + rit < cnt) {
        float wgt = ew[s * T_ + r0 + rit];
        unsigned short* hrow = h + (size_t)(hrow0 + rit) * I_ + n0 + wc * 32;
#pragma unroll
        for (int n = 0; n < 2; ++n) {
          float g = accg[m][n][r], uv = accu[m][n][r];
          float hv = g / (1.f + expf(-g)) * uv * wgt;
          hrow[n * 16 + fr] = f2bf(hv);
        }
      }
    }
}

// -------- down GEMM: out[tok] += h . wd^T (atomicAdd over slots) ------------
// tile 256(tok) x 256(H) x BK=32 over K=I; 16 waves (4r x 4c).
// Dbuf swizzled LDS (64KB), 1 barrier/K-step, loads before barrier.
__global__ __launch_bounds__(1024, 4) void k_down(
    const unsigned short* __restrict__ h,
    const float* __restrict__ wd_all, const float* __restrict__ sd_all,
    const int* __restrict__ elist,
    const int* __restrict__ ecnt, const int* __restrict__ sbase,
    float* __restrict__ out) {
  const int s = blockIdx.z;
  const int cnt = ecnt[s];
  const int r0 = blockIdx.y * 256;
  if (r0 >= cnt) return;
  const int n0 = blockIdx.x * 256;
  const float* bw = (s < E_) ? wd_all + (size_t)s * H_ * I_
                             : sd_all + (size_t)(s - E_) * H_ * I_;
  const int hrow0 = sbase[s] + r0;

  __shared__ u32x4 sA[2][256 * 4];
  __shared__ u32x4 sB[2][256 * 4];

  const int tid = threadIdx.x;
  const int w = tid >> 6, lane = tid & 63;
  const int wr = w >> 2, wc = w & 3;
  const int fr = lane & 15, k8 = lane >> 4;

  // A staging: row ar, chunk ca (8 bf16 per thread)
  const int ar = tid >> 2, ca = tid & 3;
  const unsigned short* hp = h + (size_t)(hrow0 + ar) * I_ + ca * 8;
  // B staging: row brr, 8 fp32 -> one 16B chunk per thread
  const int brr = tid >> 2, cbD = tid & 3;
  const float* bp = bw + (size_t)(n0 + brr) * I_ + cbD * 8;

  u32x4 ra; f32x4 rb0, rb1;

  f32x4 acc[4][4];
#pragma unroll
  for (int m = 0; m < 4; ++m)
#pragma unroll
    for (int n = 0; n < 4; ++n) acc[m][n] = (f32x4){0.f, 0.f, 0.f, 0.f};

  auto loadNext = [&]() {
    ra = *(const u32x4*)hp; hp += 32;
    rb0 = *(const f32x4*)bp; rb1 = *(const f32x4*)(bp + 4); bp += 32;
  };
  auto stage = [&](int b) {
    sA[b][ar * 4 + (ca ^ sw(ar))] = ra;
    u32x2 lo = cvt4(rb0), hi = cvt4(rb1);
    u32x4 q; q[0] = lo[0]; q[1] = lo[1]; q[2] = hi[0]; q[3] = hi[1];
    sB[b][brr * 4 + (cbD ^ sw(brr))] = q;
  };
  auto compute = [&](int b) {
    bf16x8 af[4], bf[4];
#pragma unroll
    for (int m = 0; m < 4; ++m) {
      int r = wr * 64 + m * 16 + fr;
      af[m] = __builtin_bit_cast(bf16x8, sA[b][r * 4 + (k8 ^ sw(r))]);
    }
#pragma unroll
    for (int n = 0; n < 4; ++n) {
      int r = wc * 64 + n * 16 + fr;
      bf[n] = __builtin_bit_cast(bf16x8, sB[b][r * 4 + (k8 ^ sw(r))]);
    }
#pragma unroll
    for (int m = 0; m < 4; ++m)
#pragma unroll
      for (int n = 0; n < 4; ++n)
        acc[m][n] = __builtin_amdgcn_mfma_f32_16x16x32_bf16(af[m], bf[n], acc[m][n], 0, 0, 0);
  };

  const int KT = I_ / 32;  // 160
  loadNext();              // kt=0
  stage(0);
  loadNext();              // kt=1 in flight
  __syncthreads();
  int cur = 0;
  for (int kt = 0; kt < KT; ++kt) {
    compute(cur);
    if (kt + 1 < KT) {
      stage(cur ^ 1);
      if (kt + 2 < KT) loadNext();  // issue BEFORE barrier
      __syncthreads();
      cur ^= 1;
    }
  }

  const int* lst = elist + s * T_;
#pragma unroll
  for (int m = 0; m < 4; ++m)
#pragma unroll
    for (int r = 0; r < 4; ++r) {
      int rit = wr * 64 + m * 16 + k8 * 4 + r;
      if (r0 + rit < cnt) {
        int t = lst[r0 + rit];
        float* orow = out + (size_t)t * H_ + n0 + wc * 64 + fr;
#pragma unroll
        for (int n = 0; n < 4; ++n) atomicAdd(orow + n * 16, acc[m][n][r]);
      }
    }
}

extern "C" void kernel_launch(void* const* d_in, const int* in_sizes, int n_in,
                              void* d_out, int out_size, void* d_ws, size_t ws_size,
                              hipStream_t stream) {
  const float* x  = (const float*)d_in[0];
  const float* wr = (const float*)d_in[1];
  const float* wg = (const float*)d_in[2];
  const float* wu = (const float*)d_in[3];
  const float* wd = (const float*)d_in[4];
  const float* sg = (const float*)d_in[5];
  const float* su = (const float*)d_in[6];
  const float* sd = (const float*)d_in[7];
  float* out = (float*)d_out;
  char* ws = (char*)d_ws;

  // workspace layout (needs ~103.1 MB; list padding now 256-aligned)
  int*   tki   = (int*)(ws);                 // T*2 ints
  float* tkw   = (float*)(ws + 16384);       // T*2 floats
  int*   elist = (int*)(ws + 32768);         // NSLOT*T ints
  float* ew    = (float*)(ws + 114688);      // NSLOT*T floats
  int*   ecnt  = (int*)(ws + 196608);        // NSLOT ints
  int*   sbase = (int*)(ws + 196864);        // NSLOT ints
  unsigned short* xb = (unsigned short*)(ws + 262144);            // T*H bf16 (8.4 MB)
  unsigned short* h  = (unsigned short*)(ws + 262144 + 8388608);  // <=10240 rows x I bf16

  k_castx<<<T_ * H_ / (256 * 8), 256, 0, stream>>>(x, xb);
  k_router<<<T_, 64, 0, stream>>>(x, wr, tki, tkw);
  k_lists<<<NSLOT, 64, 0, stream>>>(tki, tkw, elist, ew, ecnt);
  k_bases<<<1, 1, 0, stream>>>(ecnt, sbase);
  k_gateup<<<dim3(I_ / 128, T_ / 256, NSLOT), 1024, 0, stream>>>(
      xb, wg, wu, sg, su, elist, ew, ecnt, sbase, h);
  hipMemsetAsync(out, 0, (size_t)T_ * H_ * sizeof(float), stream);
  k_down<<<dim3(H_ / 256, T_ / 256, NSLOT), 1024, 0, stream>>>(
      h, wd, sd, elist, ecnt, sbase, out);
}